// Round 11
// baseline (522.242 us; speedup 1.0000x reference)
//
#include <hip/hip_runtime.h>

// Anti-alias filter: reflect-pad -> grouped conv (256->72, G=8, 3x3) -> BN ->
// softmax(72) -> per-pixel 9-tap weighted sum per channel.
// Shapes fixed: N=16, C=256, H=W=128, G=8, K=3, NCH=G*K*K=72, CPG=32.
//
// v10: v9 + pinned prefetch + block-rotated channel order.
// v9 post-mortem: VGPR stuck at 64 => compiler SANK the prefetch loads to
// their use; each ci-iter pays ~425 idle cyc (= one L2 latency), matching
// the 44% duty gap. Fixes:
//  (1) sched_barrier(0) right after issuing next-channel loads (both
//      phases): loads can't sink below it -> in flight across the 648-cyc
//      FMA block, counted vmcnt waits. VGPR rising to ~90 is the evidence.
//  (2) per-block rotation of the ci walk (rot = bid&31): the 4 co-resident
//      blocks/CU stop issuing their load bursts in lockstep. Phase 2 walks
//      descending from phase-1's last channel (L2-hottest first).
// pk_fma note kept from v8: v_pk_fma_f32 issues over 4 cyc (SIMD32, 128
// f32 lanes) so it halves instructions, not cycles; FP32 VALU floor is
// ~115us busy. The lever here is duty (56% -> target ~75%).

#define NN    16
#define CTOT  256
#define HH    128
#define WW    128
#define NG    8
#define CPG   32      // channels per group
#define NCH   72      // G*K*K conv output channels
#define BN_EPS 1e-5f

typedef float f2 __attribute__((ext_vector_type(2)));
typedef float f4 __attribute__((ext_vector_type(4)));

// ---- prep: BN scale/bias into ws ----
// ws layout (floats): [0,72) = scale, [72,144) = bias.
__global__ void aaf_prep(const float* __restrict__ gamma,
                         const float* __restrict__ beta,
                         const float* __restrict__ rmean,
                         const float* __restrict__ rvar,
                         float* __restrict__ ws) {
    int t = threadIdx.x;
    if (t < NCH) {
        float sc = gamma[t] * rsqrtf(rvar[t] + BN_EPS);
        ws[t]       = sc;
        ws[NCH + t] = beta[t] - rmean[t] * sc;
    }
}

// ---- main: block = 8 waves = 8 groups; wave = 2 rows x 128 px (4 px/lane) ----
__global__ __launch_bounds__(512) void aaf_main(
    const float* __restrict__ x,
    const float* __restrict__ wf,     // fp32 conv weights OIHW flat (wave-uniform -> s_load)
    const float* __restrict__ scale,  // fp32 BN scale (72)
    const float* __restrict__ bias,   // fp32 BN bias  (72)
    float* __restrict__ out) {

    __shared__ f4 red_m[NG][64];      // per-group softmax max, 4 px per slot (8 KB)
    __shared__ f4 red_s[NG][64];      // per-group exp-sum (8 KB)

    int t  = threadIdx.x & 63;                                     // lane
    int g  = __builtin_amdgcn_readfirstlane((int)threadIdx.x >> 6);// group = wave id
    int half = t >> 5;                // 0: row A, 1: row B
    int tl   = t & 31;                // lane within row
    int w0   = tl << 2;               // first of this lane's 4 pixels

    // 1024 blocks = one row-pair each; bijective XCD-chunked swizzle: each XCD
    // walks 128 consecutive row-pairs (2 images) -> vertical halo reuse in-L2.
    int bid = blockIdx.x;
    int pr  = (bid & 7) * (1024 / 8) + (bid >> 3);
    int n   = pr >> 6;                // 64 row-pairs per image
    int h   = ((pr & 63) << 1) + half;
    int rot = bid & 31;               // per-block channel-walk rotation

    // reflection-pad row indices (pad=1): -1 -> 1, 128 -> 126
    int ys[3];
    ys[0] = (h == 0)   ? 1   : h - 1;
    ys[1] = h;
    ys[2] = (h == 127) ? 126 : h + 1;

    // this wave's 32 input channels start at g*CPG
    const float* xg = x + ((size_t)n << 22) + ((size_t)(g * CPG) << 14);

    f2 S01[9], S23[9];
#pragma unroll
    for (int o = 0; o < 9; o++) { S01[o] = (f2)0.f; S23[o] = (f2)0.f; }

    // ---- grouped conv, packed fp32, pinned ci+1 register prefetch ----
    f4 cur[3];
    {
        const float* xc0 = xg + ((size_t)rot << 14);
#pragma unroll
        for (int ky = 0; ky < 3; ky++)
            cur[ky] = *reinterpret_cast<const f4*>(xc0 + (ys[ky] << 7) + w0);
    }

#pragma unroll 2
    for (int lin = 0; lin < CPG; lin++) {
        int ci  = (lin + rot) & 31;
        int cin = ((lin + 1 < CPG ? lin + 1 : lin) + rot) & 31;
        const float* xcn = xg + ((size_t)cin << 14);
        f4 nxt[3];
#pragma unroll
        for (int ky = 0; ky < 3; ky++)
            nxt[ky] = *reinterpret_cast<const f4*>(xcn + (ys[ky] << 7) + w0);
        __builtin_amdgcn_sched_barrier(0);   // pin: loads may not sink below

        // build tap pairs from cur
        f2 P[3][5];
#pragma unroll
        for (int ky = 0; ky < 3; ky++) {
            f4 vv = cur[ky];
            float l = __shfl_up(vv.w, 1);     // x[w0-1]
            l = (tl == 0) ? vv.y : l;         // left edge: reflect -> x[1]
            float r = __shfl_down(vv.x, 1);   // x[w0+4]
            r = (tl == 31) ? vv.z : r;        // right edge: reflect -> x[126]
            P[ky][0] = (f2){l,    vv.x};
            P[ky][1] = (f2){vv.x, vv.y};
            P[ky][2] = (f2){vv.y, vv.z};
            P[ky][3] = (f2){vv.z, vv.w};
            P[ky][4] = (f2){vv.w, r};
        }
        const float* wb = wf + (size_t)(g * 9) * (CPG * 9) + ci * 9;
#pragma unroll
        for (int o = 0; o < 9; o++) {
            const float* wo = wb + o * (CPG * 9);
            f2 a01 = S01[o], a23 = S23[o];
#pragma unroll
            for (int ky = 0; ky < 3; ky++) {
                f2 w0b = (f2)wo[ky * 3 + 0];   // scalar->vector splat
                f2 w1b = (f2)wo[ky * 3 + 1];
                f2 w2b = (f2)wo[ky * 3 + 2];
                a01 = __builtin_elementwise_fma(P[ky][0], w0b,
                      __builtin_elementwise_fma(P[ky][1], w1b,
                      __builtin_elementwise_fma(P[ky][2], w2b, a01)));
                a23 = __builtin_elementwise_fma(P[ky][2], w0b,
                      __builtin_elementwise_fma(P[ky][3], w1b,
                      __builtin_elementwise_fma(P[ky][4], w2b, a23)));
            }
            S01[o] = a01; S23[o] = a23;
        }
#pragma unroll
        for (int ky = 0; ky < 3; ky++) cur[ky] = nxt[ky];
    }

    // ---- BN + per-group (unnormalized) softmax over this group's 9 ----
    float s0[9], s1[9], s2[9], s3[9];
    float m0 = -3.0e38f, m1 = -3.0e38f, m2 = -3.0e38f, m3 = -3.0e38f;
#pragma unroll
    for (int o = 0; o < 9; o++) {
        float sc = scale[g * 9 + o], bi = bias[g * 9 + o];
        s0[o] = fmaf(S01[o].x, sc, bi);  m0 = fmaxf(m0, s0[o]);
        s1[o] = fmaf(S01[o].y, sc, bi);  m1 = fmaxf(m1, s1[o]);
        s2[o] = fmaf(S23[o].x, sc, bi);  m2 = fmaxf(m2, s2[o]);
        s3[o] = fmaf(S23[o].y, sc, bi);  m3 = fmaxf(m3, s3[o]);
    }
    float S0 = 0.f, S1 = 0.f, S2 = 0.f, S3 = 0.f;
#pragma unroll
    for (int o = 0; o < 9; o++) {
        s0[o] = __expf(s0[o] - m0);  S0 += s0[o];   // s* now holds E
        s1[o] = __expf(s1[o] - m1);  S1 += s1[o];
        s2[o] = __expf(s2[o] - m2);  S2 += s2[o];
        s3[o] = __expf(s3[o] - m3);  S3 += s3[o];
    }
    {
        f4 mm; mm.x = m0; mm.y = m1; mm.z = m2; mm.w = m3;
        f4 ss; ss.x = S0; ss.y = S1; ss.z = S2; ss.w = S3;
        red_m[g][t] = mm;             // slot t = pixels [half*128 + w0 .. +3]
        red_s[g][t] = ss;
    }

    // ---- single barrier: combine the 8 groups' (m,S) into 1/denom ----
    __syncthreads();
    float d0 = 0.f, d1 = 0.f, d2 = 0.f, d3 = 0.f;
#pragma unroll
    for (int rg = 0; rg < NG; rg++) {
        f4 mm = red_m[rg][t];
        f4 ss = red_s[rg][t];
        d0 += ss.x * __expf(mm.x - m0);
        d1 += ss.y * __expf(mm.y - m1);
        d2 += ss.z * __expf(mm.z - m2);
        d3 += ss.w * __expf(mm.w - m3);
    }
    float i0 = 1.f / d0, i1 = 1.f / d1, i2 = 1.f / d2, i3 = 1.f / d3;
#pragma unroll
    for (int o = 0; o < 9; o++) { s0[o] *= i0; s1[o] *= i1; s2[o] *= i2; s3[o] *= i3; }

    // ---- weighted 9-tap sum, descending from phase-1's last channel ----
    size_t obase = ((size_t)n << 22) + ((size_t)(g * CPG) << 14)
                 + ((size_t)h << 7) + (size_t)w0;
    f4 cur2[3];
    {
        const float* xc0 = xg + ((size_t)((rot + 31) & 31) << 14);
#pragma unroll
        for (int ky = 0; ky < 3; ky++)
            cur2[ky] = *reinterpret_cast<const f4*>(xc0 + (ys[ky] << 7) + w0);
    }

#pragma unroll 2
    for (int lin = 0; lin < CPG; lin++) {
        int ci  = (rot + 31 - lin) & 31;
        int cin = (rot + 31 - (lin + 1 < CPG ? lin + 1 : lin)) & 31;
        const float* xcn = xg + ((size_t)cin << 14);
        f4 nxt[3];
#pragma unroll
        for (int ky = 0; ky < 3; ky++)
            nxt[ky] = *reinterpret_cast<const f4*>(xcn + (ys[ky] << 7) + w0);
        __builtin_amdgcn_sched_barrier(0);   // pin: loads may not sink below

        float o0 = 0.f, o1 = 0.f, o2 = 0.f, o3 = 0.f;
#pragma unroll
        for (int ky = 0; ky < 3; ky++) {
            f4 vv = cur2[ky];
            float l = __shfl_up(vv.w, 1);
            l = (tl == 0) ? vv.y : l;
            float r = __shfl_down(vv.x, 1);
            r = (tl == 31) ? vv.z : r;
            float e0 = s0[ky * 3 + 0], e1 = s0[ky * 3 + 1], e2 = s0[ky * 3 + 2];
            o0 = fmaf(l,    e0, fmaf(vv.x, e1, fmaf(vv.y, e2, o0)));
            e0 = s1[ky * 3 + 0]; e1 = s1[ky * 3 + 1]; e2 = s1[ky * 3 + 2];
            o1 = fmaf(vv.x, e0, fmaf(vv.y, e1, fmaf(vv.z, e2, o1)));
            e0 = s2[ky * 3 + 0]; e1 = s2[ky * 3 + 1]; e2 = s2[ky * 3 + 2];
            o2 = fmaf(vv.y, e0, fmaf(vv.z, e1, fmaf(vv.w, e2, o2)));
            e0 = s3[ky * 3 + 0]; e1 = s3[ky * 3 + 1]; e2 = s3[ky * 3 + 2];
            o3 = fmaf(vv.z, e0, fmaf(vv.w, e1, fmaf(r,    e2, o3)));
        }
        f4 ov; ov.x = o0; ov.y = o1; ov.z = o2; ov.w = o3;
        __builtin_nontemporal_store(ov,
            reinterpret_cast<f4*>(out + obase + ((size_t)ci << 14)));
#pragma unroll
        for (int ky = 0; ky < 3; ky++) cur2[ky] = nxt[ky];
    }
}

extern "C" void kernel_launch(void* const* d_in, const int* in_sizes, int n_in,
                              void* d_out, int out_size, void* d_ws, size_t ws_size,
                              hipStream_t stream) {
    const float* x     = (const float*)d_in[0];
    const float* cw    = (const float*)d_in[1];
    const float* gamma = (const float*)d_in[2];
    const float* beta  = (const float*)d_in[3];
    const float* rmean = (const float*)d_in[4];
    const float* rvar  = (const float*)d_in[5];
    float* out = (float*)d_out;
    float* ws  = (float*)d_ws;   // needs 144*4 = 576 B

    hipLaunchKernelGGL(aaf_prep, dim3(1), dim3(128), 0, stream,
                       gamma, beta, rmean, rvar, ws);

    int blocks = NN * HH / 2;           // 1024 blocks: one row-pair x 8 groups
    hipLaunchKernelGGL(aaf_main, dim3(blocks), dim3(512), 0, stream,
                       x, cw, ws, ws + NCH, out);
}